// Round 8
// baseline (155.648 us; speedup 1.0000x reference)
//
#include <hip/hip_runtime.h>
#include <hip/hip_bf16.h>

#define HDIM 256
#define HPDIM 128

typedef short bf8 __attribute__((ext_vector_type(8)));   // 8 bf16 in 4 VGPRs
typedef float f32x4 __attribute__((ext_vector_type(4)));

__device__ inline unsigned pkbf2(float a, float b) {
  float2 f; f.x = a; f.y = b;
  __hip_bfloat162 h = __float22bfloat162_rn(f);          // v_cvt_pk_bf16_f32 (RNE)
  unsigned u; __builtin_memcpy(&u, &h, 4); return u;
}
__device__ inline unsigned short bfbits(float v) {
  __hip_bfloat16 h = __float2bfloat16(v);
  unsigned short u; __builtin_memcpy(&u, &h, 2); return u;
}
__device__ inline uint4 pack8u(float4 a, float4 b) {
  uint4 r;
  r.x = pkbf2(a.x, a.y); r.y = pkbf2(a.z, a.w);
  r.z = pkbf2(b.x, b.y); r.w = pkbf2(b.z, b.w);
  return r;
}
__device__ inline float fast_tanh(float x) {
  float t = __expf(2.0f * x);
  return 1.0f - 2.0f * __builtin_amdgcn_rcpf(t + 1.0f);
}
// gather 8 consecutive fp32 weights -> bf16 MFMA fragment
__device__ inline bf8 wfrag(const float* __restrict__ s) {
  float4 a = *(const float4*)s, b = *(const float4*)(s + 4);
  uint4 u = pack8u(a, b);
  bf8 r; __builtin_memcpy(&r, &u, 16); return r;
}

typedef const __attribute__((address_space(1))) unsigned int* gas_ptr;
typedef __attribute__((address_space(3))) unsigned int* las_ptr;
__device__ inline void gld_lds16(const void* g, void* l) {
  __builtin_amdgcn_global_load_lds((gas_ptr)g, (las_ptr)l, 16, 0, 0);
}

// ---------------- Kernel 0: prep -----------------------------------------
// blocks 0..63 : front MLP (self-gathered weight fragments) -> x3f
// blocks 64..79: msg[b][h] -> msgTT[(h>>2)*4096 + b*4 + (h&3)]
__global__ __launch_bounds__(256) void k_prep(
    const float* __restrict__ h0, const float* __restrict__ htv,
    const float* __restrict__ cp,
    const float* __restrict__ w1, const float* __restrict__ w2,
    const float* __restrict__ w3, const float* __restrict__ msg,
    short* __restrict__ x3f, float* __restrict__ msgTT) {
  const int t = threadIdx.x;
  const int bx = blockIdx.x;

  if (bx >= 64) {                      // ---- msg transpose: 16 blocks
    const int b0 = (bx - 64) * 64;
    #pragma unroll
    for (int it = 0; it < 16; ++it) {
      int u = it * 256 + t;            // 4096 (g,b) float4 pairs
      int bl = u & 63, g = u >> 6;
      float4 v = *(const float4*)(msg + (size_t)(b0 + bl) * HDIM + g * 4);
      *(float4*)(msgTT + (size_t)g * 4096 + (b0 + bl) * 4) = v;   // coalesced write
    }
    return;
  }

  // ---- front MLP: 64 blocks x 16 b ----
  __shared__ char hbuf[8192];    // 16 x 256 bf16, swizzled 16B chunks
  __shared__ char xa[4096];      // 16 x 128 bf16, swizzled
  __shared__ char xb[4096];
  const int wave = t >> 6, lane = t & 63;
  const int r16 = lane & 15, quad = lane >> 4;
  const int b0 = bx * 16;
  const float cc = fminf(fmaxf(cp[0], 0.f), 1.f);

  // stage h = cc*h0+(1-cc)*ht (16x256)
  #pragma unroll
  for (int it = 0; it < 2; ++it) {
    int flat = it * 2048 + t * 8;
    int row = flat >> 8, col = flat & 255, kb = col >> 3;
    int gi = (b0 + row) * HDIM + col;
    float4 a = *(const float4*)(h0 + gi);
    float4 b = *(const float4*)(htv + gi);
    float4 va, vb;
    va.x = cc*a.x + (1.f-cc)*b.x; va.y = cc*a.y + (1.f-cc)*b.y;
    va.z = cc*a.z + (1.f-cc)*b.z; va.w = cc*a.w + (1.f-cc)*b.w;
    a = *(const float4*)(h0 + gi + 4); b = *(const float4*)(htv + gi + 4);
    vb.x = cc*a.x + (1.f-cc)*b.x; vb.y = cc*a.y + (1.f-cc)*b.y;
    vb.z = cc*a.z + (1.f-cc)*b.z; vb.w = cc*a.w + (1.f-cc)*b.w;
    *(uint4*)(hbuf + row*512 + ((kb ^ (row & 7)) << 4)) = pack8u(va, vb);
  }
  __syncthreads();

  // layer 1: [16 x 256] @ w1^T -> xa
  {
    f32x4 acc[2] = {};
    #pragma unroll
    for (int ks = 0; ks < 8; ++ks) {
      bf8 af = *(bf8*)(hbuf + r16*512 + (((ks*4 + quad) ^ (r16 & 7)) << 4));
      #pragma unroll
      for (int nt = 0; nt < 2; ++nt) {
        bf8 bw_ = wfrag(w1 + ((wave*2 + nt)*16 + r16) * 256 + ks*32 + quad*8);
        acc[nt] = __builtin_amdgcn_mfma_f32_16x16x32_bf16(af, bw_, acc[nt], 0, 0, 0);
      }
    }
    #pragma unroll
    for (int nt = 0; nt < 2; ++nt)
      #pragma unroll
      for (int i = 0; i < 4; ++i) {
        int row = quad*4 + i, col = wave*32 + nt*16 + r16;
        *(unsigned short*)(xa + row*256 + (((col >> 3) ^ (row & 7)) << 4) + ((col & 7) << 1))
            = bfbits(fast_tanh(acc[nt][i]));
      }
  }
  __syncthreads();
  // layer 2: xa @ w2^T -> xb
  {
    f32x4 acc[2] = {};
    #pragma unroll
    for (int ks = 0; ks < 4; ++ks) {
      bf8 af = *(bf8*)(xa + r16*256 + (((ks*4 + quad) ^ (r16 & 7)) << 4));
      #pragma unroll
      for (int nt = 0; nt < 2; ++nt) {
        bf8 bw_ = wfrag(w2 + ((wave*2 + nt)*16 + r16) * 128 + ks*32 + quad*8);
        acc[nt] = __builtin_amdgcn_mfma_f32_16x16x32_bf16(af, bw_, acc[nt], 0, 0, 0);
      }
    }
    #pragma unroll
    for (int nt = 0; nt < 2; ++nt)
      #pragma unroll
      for (int i = 0; i < 4; ++i) {
        int row = quad*4 + i, col = wave*32 + nt*16 + r16;
        *(unsigned short*)(xb + row*256 + (((col >> 3) ^ (row & 7)) << 4) + ((col & 7) << 1))
            = bfbits(fast_tanh(acc[nt][i]));
      }
  }
  __syncthreads();
  // layer 3: xb @ w3^T -> xa
  {
    f32x4 acc[2] = {};
    #pragma unroll
    for (int ks = 0; ks < 4; ++ks) {
      bf8 af = *(bf8*)(xb + r16*256 + (((ks*4 + quad) ^ (r16 & 7)) << 4));
      #pragma unroll
      for (int nt = 0; nt < 2; ++nt) {
        bf8 bw_ = wfrag(w3 + ((wave*2 + nt)*16 + r16) * 128 + ks*32 + quad*8);
        acc[nt] = __builtin_amdgcn_mfma_f32_16x16x32_bf16(af, bw_, acc[nt], 0, 0, 0);
      }
    }
    #pragma unroll
    for (int nt = 0; nt < 2; ++nt)
      #pragma unroll
      for (int i = 0; i < 4; ++i) {
        int row = quad*4 + i, col = wave*32 + nt*16 + r16;
        *(unsigned short*)(xa + row*256 + (((col >> 3) ^ (row & 7)) << 4) + ((col & 7) << 1))
            = bfbits(fast_tanh(acc[nt][i]));
      }
  }
  __syncthreads();
  // dump xa -> x3f in B-fragment order
  {
    int ks = t >> 6, l = t & 63, q2 = l >> 4, rr = l & 15;
    uint4 d = *(uint4*)(xa + rr*256 + (((ks*4 + q2) ^ (rr & 7)) << 4));
    *(uint4*)(x3f + (size_t)((bx*4 + ks)*64 + l)*8) = d;
  }
}

// ---------------- Kernel 1/2: fused hypernetwork GEMM --------------------
// PHASE 0: g1TT[k,b] = tanh( sum_h msgTT[h,b] * (fc4[kcol*256+h,:] . x3[b,:]) )
// PHASE 1: out[b,kcol] =     sum_k g1TT[k,b]  * (fc4[65536+kcol*256+k,:] . x3[b,:])
// Round-8 change: the fp32 slab is staged via global_load_lds DMA (deep HW
// queue, no dest VGPRs) into a 3-buffer 16 KB ring, converted chunk-by-chunk
// (32 rows) to the swizzled bf16 slab under a counted-vmcnt pipeline (raw
// s_barrier + vmcnt(1): next chunk's DMA stays in flight across the barrier).
// Rationale: reg-staging at ~120 live VGPRs can't keep enough loads in
// flight -> stage was latency-bound (~2-4x the 5 us HBM floor), the main
// residual of the ~31 us hyper. xf stays pinned (no remat).
template<int PHASE>
__global__ __launch_bounds__(1024, 4) void k_hyper(
    const short* __restrict__ x3f, const float* __restrict__ wTT,
    const float* __restrict__ fc4, float* __restrict__ outp) {
  __shared__ char lds[65536 + 49152];      // bf16 slab (swizzled) + fp32 3-ring
  char* slab = lds;
  char* ring = lds + 65536;
  const int bxs = blockIdx.x;
  const int kcol = ((bxs & 7) << 5) | (bxs >> 3);   // bijective XCD grouping
  const int t = threadIdx.x, wave = t >> 6, lane = t & 63;
  const int r16 = lane & 15, quad = lane >> 4;
  const int bw = wave * 64;                // this wave's 64-b slice

  const float* src = fc4 + ((size_t)(PHASE ? 65536 : 0) + (size_t)kcol * 256) * HPDIM;

  // prologue: DMA chunk 0 (32 rows, 16 KB; 1 dwordx4 per thread, linear dest)
  gld_lds16(src + t * 4, ring + t * 16);

  // x3 B-fragments (16 x b128 per thread = 64 VGPRs), pinned live
  bf8 xf[4][4];
  #pragma unroll
  for (int nt = 0; nt < 4; ++nt)
    #pragma unroll
    for (int ks = 0; ks < 4; ++ks)
      xf[nt][ks] = *(const bf8*)(x3f +
          (size_t)(((wave*4 + nt)*4 + ks)*64 + lane)*8);
  #pragma unroll
  for (int nt = 0; nt < 4; ++nt)
    #pragma unroll
    for (int ks = 0; ks < 4; ++ks)
      asm volatile("" : "+v"(xf[nt][ks]));   // opaque def: no remat possible

  // DMA->convert pipeline: issue c+1, wait c (vmcnt(1), NOT 0), convert c.
  #pragma unroll
  for (int c = 0; c < 8; ++c) {
    if (c < 7)
      gld_lds16(src + (c + 1) * 4096 + t * 4, ring + ((c + 1) % 3) * 16384 + t * 16);
    if (c < 7) asm volatile("s_waitcnt vmcnt(1) lgkmcnt(0)" ::: "memory");
    else       asm volatile("s_waitcnt vmcnt(0) lgkmcnt(0)" ::: "memory");
    __builtin_amdgcn_s_barrier();
    __builtin_amdgcn_sched_barrier(0);
    // convert chunk c: 4 fp32 -> 4 bf16 per thread, swizzled 8B write
    {
      f32x4 v = *(const f32x4*)(ring + (c % 3) * 16384 + t * 16);
      int row = c * 32 + (t >> 5), kb = (t & 31) >> 1;
      uint2 o; o.x = pkbf2(v[0], v[1]); o.y = pkbf2(v[2], v[3]);
      *(uint2*)(slab + row * 256 + ((kb ^ (row & 7)) << 4) + (t & 1) * 8) = o;
    }
  }
  __syncthreads();                         // slab complete (nothing in flight)

  float gacc[4] = {0.f, 0.f, 0.f, 0.f};
  const float* wbase = wTT + (size_t)quad * 4096 + (bw + r16) * 4;

  #pragma unroll 1
  for (int hg = 0; hg < 16; ++hg) {
    float4 wv[4];
    #pragma unroll
    for (int nt = 0; nt < 4; ++nt)         // L2 loads first (consumed post-MFMA)
      wv[nt] = *(const float4*)(wbase + (size_t)hg*16384 + nt*64);
    const int row = hg*16 + r16;
    bf8 af[4];
    #pragma unroll
    for (int ks = 0; ks < 4; ++ks)
      af[ks] = *(bf8*)(slab + row*256 + (((ks*4 + quad) ^ (row & 7)) << 4));
    #pragma unroll
    for (int nt = 0; nt < 4; ++nt) {
      f32x4 acc = {};
      #pragma unroll
      for (int ks = 0; ks < 4; ++ks)
        acc = __builtin_amdgcn_mfma_f32_16x16x32_bf16(af[ks], xf[nt][ks], acc, 0, 0, 0);
      gacc[nt] += acc[0]*wv[nt].x + acc[1]*wv[nt].y + acc[2]*wv[nt].z + acc[3]*wv[nt].w;
    }
  }

  #pragma unroll
  for (int nt = 0; nt < 4; ++nt) {
    float v = gacc[nt];
    v += __shfl_xor(v, 16);
    v += __shfl_xor(v, 32);
    if (quad == 0) {
      int b = bw + nt*16 + r16;
      if (PHASE == 0) outp[(size_t)(kcol >> 2)*4096 + b*4 + (kcol & 3)] = fast_tanh(v);
      else            outp[b*HDIM + kcol] = v;
    }
  }
}

extern "C" void kernel_launch(void* const* d_in, const int* in_sizes, int n_in,
                              void* d_out, int out_size, void* d_ws, size_t ws_size,
                              hipStream_t stream) {
  const float* h0  = (const float*)d_in[0];
  const float* htt = (const float*)d_in[1];
  const float* msg = (const float*)d_in[2];
  const float* c   = (const float*)d_in[3];
  const float* w1  = (const float*)d_in[4];
  const float* w2  = (const float*)d_in[5];
  const float* w3  = (const float*)d_in[6];
  const float* w4  = (const float*)d_in[7];
  float* out = (float*)d_out;

  short* x3f  = (short*)d_ws;                              // 256 KB
  float* g1TT = (float*)((char*)d_ws + 262144);            // 1 MB
  float* msgTT= (float*)((char*)d_ws + 262144 + 1048576);  // 1 MB

  k_prep<<<dim3(80), dim3(256), 0, stream>>>(h0, htt, c, w1, w2, w3, msg,
                                             x3f, msgTT);
  k_hyper<0><<<dim3(256), dim3(1024), 0, stream>>>(x3f, msgTT, w4, g1TT);
  k_hyper<1><<<dim3(256), dim3(1024), 0, stream>>>(x3f, g1TT, w4, out);
}